// Round 7
// baseline (110.896 us; speedup 1.0000x reference)
//
#include <hip/hip_runtime.h>
#include <hip/hip_bf16.h>
#include <math.h>

// ---- constants mirroring the reference ----
#define TWO_PI_D 6.283185307179586
constexpr int   NOFF  = 32768;
constexpr int   NSAMP = 128;
constexpr int   NRF   = 4;
constexpr int   NSTEP = NRF * NSAMP;   // 512
constexpr float DT    = 3.9e-05f;
constexpr float R1A   = 1.0f / 1.3f;
constexpr float R2A   = 1.0f / 0.075f;
constexpr float R1B   = 1.0f;
constexpr float R2B   = 30.0f;
constexpr float KBv   = 200.0f;
constexpr float FBv   = 0.01f;
constexpr float KAv   = FBv * KBv;     // 2.0
constexpr float DWB   = 447.0f;

typedef float f32x2 __attribute__((ext_vector_type(2)));

// ---- VOP3P packed-f32 helpers (64-bit VGPR pairs, 2 f32 per lane) ----
#define PK_MUL(d, a, b) \
    asm("v_pk_mul_f32 %0, %1, %2" : "=v"(d) : "v"(a), "v"(b))
#define PK_ADD(d, a, b) \
    asm("v_pk_add_f32 %0, %1, %2" : "=v"(d) : "v"(a), "v"(b))
#define PK_FMA(d, a, b, c) \
    asm("v_pk_fma_f32 %0, %1, %2, %3" : "=v"(d) : "v"(a), "v"(b), "v"(c))
#define PK_FMA_ACC(acc, a, b) \
    asm("v_pk_fma_f32 %0, %1, %2, %0" : "+v"(acc) : "v"(a), "v"(b))
#define PK_FMA_ACC_NEG0(acc, a, b) \
    asm("v_pk_fma_f32 %0, %1, %2, %0 neg_lo:[1,0,0] neg_hi:[1,0,0]" : "+v"(acc) : "v"(a), "v"(b))
// src0 = (ws,wc) table pair; dup LOW half (ws) into both mul lanes
#define PK_FMA_ACC_WSLO(acc, w, b) \
    asm("v_pk_fma_f32 %0, %1, %2, %0 op_sel:[0,0,0] op_sel_hi:[0,1,1]" : "+v"(acc) : "v"(w), "v"(b))
#define PK_FMA_ACC_WSLO_NEG(acc, w, b) \
    asm("v_pk_fma_f32 %0, %1, %2, %0 op_sel:[0,0,0] op_sel_hi:[0,1,1] neg_lo:[1,0,0] neg_hi:[1,0,0]" : "+v"(acc) : "v"(w), "v"(b))
// dup HIGH half (wc) into both mul lanes
#define PK_FMA_ACC_WCHI(acc, w, b) \
    asm("v_pk_fma_f32 %0, %1, %2, %0 op_sel:[1,0,0] op_sel_hi:[1,1,1]" : "+v"(acc) : "v"(w), "v"(b))
#define PK_FMA_ACC_WCHI_NEG(acc, w, b) \
    asm("v_pk_fma_f32 %0, %1, %2, %0 op_sel:[1,0,0] op_sel_hi:[1,1,1] neg_lo:[1,0,0] neg_hi:[1,0,0]" : "+v"(acc) : "v"(w), "v"(b))
// d = a * swap(s)   (exchange coupling: lo = a.lo*s.hi, hi = a.hi*s.lo)
#define PK_MUL_SWAP1(d, a, s) \
    asm("v_pk_mul_f32 %0, %1, %2 op_sel:[0,1] op_sel_hi:[1,0]" : "=v"(d) : "v"(a), "v"(s))
// d = a * swap(s) + c
#define PK_FMA_SWAP1(d, a, s, c) \
    asm("v_pk_fma_f32 %0, %1, %2, %3 op_sel:[0,1,0] op_sel_hi:[1,0,1]" : "=v"(d) : "v"(a), "v"(s), "v"(c))

struct AccPh { float a[8]; };          // [sim][rf_block] accumulated phase

// Precompute per-(sim, sample): ws = w1*sin(ph_eff)*DT, wc = w1*cos(ph_eff)*DT
__global__ void precomp_kernel(const float* __restrict__ amps,
                               const float* __restrict__ phases,
                               AccPh acc, float2* __restrict__ wsc) {
    int tid = blockIdx.x * blockDim.x + threadIdx.x;   // 0..1023
    if (tid >= 2 * NSTEP) return;
    int sim = tid >> 9;          // 0: +200 Hz, 1: -200 Hz
    int idx = tid & (NSTEP - 1); // r*128 + i
    int r   = idx >> 7;
    float ph = -phases[idx] - acc.a[sim * 4 + r];
    float w1 = (float)(TWO_PI_D * 42.577) * amps[idx];
    wsc[tid] = make_float2(w1 * sinf(ph) * DT, w1 * cosf(ph) * DT);
}

__global__ void init_kernel(unsigned int* g) {
    if (threadIdx.x < 2) g[threadIdx.x] = 0u;
}

__global__ __launch_bounds__(256) void bmc_kernel(
        const float* __restrict__ offsets,
        const float* __restrict__ m_init,
        const float2* __restrict__ wsc,
        unsigned int* __restrict__ gmax) {
    int tid = blockIdx.x * blockDim.x + threadIdx.x;   // 0..65535
    int sim = tid >> 15;
    int o   = tid & (NOFF - 1);

    const float TP  = (float)TWO_PI_D;
    float rf  = sim ? -200.0f : 200.0f;
    float off = offsets[o];
    float dwa = TP * (off - rf);
    float dwb = TP * ((off + DWB) - rf);

    // Pair layout: A=(m0,m3), B=(m1,m4), C=(m2,m5).
    const f32x2 CA2 = { -(R2A + KAv) * DT, -(R2B + KBv) * DT };  // transverse diags
    const f32x2 CB2 = { -(R1A + KAv) * DT, -(R1B + KBv) * DT };  // longitudinal diags
    const f32x2 DW2 = { dwa * DT, dwb * DT };
    const f32x2 KX2 = { KBv * DT, KAv * DT };                    // (kb, ka)
    const f32x2 BP2 = { R1A * DT, R1B * FBv * DT };              // b-vector rows 2,5
    const f32x2 CK2 = { 0.5f, 0.5f };
    const f32x2 CQ4 = { 0.25f, 0.25f };
    const f32x2 CS6 = { 1.0f / 6.0f, 1.0f / 6.0f };

    f32x2 mA = { m_init[0], m_init[3] };
    f32x2 mB = { m_init[1], m_init[4] };
    f32x2 mC = { m_init[2], m_init[5] };
    float lmax = 0.0f;

    // Tree-form matvec d = X * s: per output row two INDEPENDENT depth-2
    // chains (diag+dw rotation | exchange-swap+RF rotation) combined by one
    // add -> 6 parallel chains, depth 3 (vs 3 chains depth 4 in round 6).
    // At 1 wave/SIMD all latency hiding must come from ILP; this doubles the
    // number of in-flight independent pk ops at every level.
#define TERMX_TREE(sA, sB, sC, dA, dB, dC, W)    \
    {                                            \
        f32x2 a1, a2, b1, b2, c1, c2;            \
        PK_MUL(a1, CA2, sA);                     \
        PK_MUL(b1, CA2, sB);                     \
        PK_MUL(c1, CB2, sC);                     \
        PK_MUL_SWAP1(a2, KX2, sA);               \
        PK_MUL_SWAP1(b2, KX2, sB);               \
        PK_MUL_SWAP1(c2, KX2, sC);               \
        PK_FMA_ACC(a1, DW2, sB);                 \
        PK_FMA_ACC_NEG0(b1, DW2, sA);            \
        PK_FMA_ACC_WSLO(c1, W, sA);              \
        PK_FMA_ACC_WSLO_NEG(a2, W, sC);          \
        PK_FMA_ACC_WCHI(b2, W, sC);              \
        PK_FMA_ACC_WCHI_NEG(c2, W, sB);          \
        PK_ADD(dA, a1, a2);                      \
        PK_ADD(dB, b1, b2);                      \
        PK_ADD(dC, c1, c2);                      \
    }
    // First-term variant: fold b' into the exchange-chain start of row C.
#define TERMX_TREE_B(sA, sB, sC, dA, dB, dC, W)  \
    {                                            \
        f32x2 a1, a2, b1, b2, c1, c2;            \
        PK_MUL(a1, CA2, sA);                     \
        PK_MUL(b1, CA2, sB);                     \
        PK_MUL(c1, CB2, sC);                     \
        PK_MUL_SWAP1(a2, KX2, sA);               \
        PK_MUL_SWAP1(b2, KX2, sB);               \
        PK_FMA_SWAP1(c2, KX2, sC, BP2);          \
        PK_FMA_ACC(a1, DW2, sB);                 \
        PK_FMA_ACC_NEG0(b1, DW2, sA);            \
        PK_FMA_ACC_WSLO(c1, W, sA);              \
        PK_FMA_ACC_WSLO_NEG(a2, W, sC);          \
        PK_FMA_ACC_WCHI(b2, W, sC);              \
        PK_FMA_ACC_WCHI_NEG(c2, W, sB);          \
        PK_ADD(dA, a1, a2);                      \
        PK_ADD(dB, b1, b2);                      \
        PK_ADD(dC, c1, c2);                      \
    }

    // Degree-4 Taylor step; accumulation tree-reduced:
    // m += (u1 + u2/2) + (u3 + u4/4)/6   -- m-chain is a single add, off
    // the u-chain critical path until the very end.
#define BMC_STEP(W)                                                           \
    {                                                                         \
        f32x2 u1A, u1B, u1C, u2A, u2B, u2C, u3A, u3B, u3C, u4A, u4B, u4C;     \
        f32x2 t1A, t1B, t1C, t2A, t2B, t2C;                                   \
        TERMX_TREE_B(mA, mB, mC, u1A, u1B, u1C, W)                            \
        TERMX_TREE(u1A, u1B, u1C, u2A, u2B, u2C, W)                           \
        PK_FMA(t1A, CK2, u2A, u1A);                                           \
        PK_FMA(t1B, CK2, u2B, u1B);                                           \
        PK_FMA(t1C, CK2, u2C, u1C);                                           \
        TERMX_TREE(u2A, u2B, u2C, u3A, u3B, u3C, W)                           \
        TERMX_TREE(u3A, u3B, u3C, u4A, u4B, u4C, W)                           \
        PK_FMA(t2A, CQ4, u4A, u3A);                                           \
        PK_FMA(t2B, CQ4, u4B, u3B);                                           \
        PK_FMA(t2C, CQ4, u4C, u3C);                                           \
        PK_FMA_ACC(t1A, CS6, t2A);                                            \
        PK_FMA_ACC(t1B, CS6, t2B);                                            \
        PK_FMA_ACC(t1C, CS6, t2C);                                            \
        PK_ADD(mA, mA, t1A);                                                  \
        PK_ADD(mB, mB, t1B);                                                  \
        PK_ADD(mC, mC, t1C);                                                  \
        lmax = fmaxf(lmax, fmaf(mA.x, mA.x, mB.x * mB.x));                    \
    }

    // 8 steps per iteration; four float4 loads prefetched one iteration ahead
    const float4* __restrict__ w4 = (const float4*)(wsc + sim * NSTEP); // 256 x float4
    float4 p0 = w4[0], p1 = w4[1], p2 = w4[2], p3 = w4[3];
    for (int j = 0; j < NSTEP / 8; ++j) {
        int jn = (j + 1) & (NSTEP / 8 - 1);          // wraps to 0 on last iter
        float4 n0 = w4[4 * jn];
        float4 n1 = w4[4 * jn + 1];
        float4 n2 = w4[4 * jn + 2];
        float4 n3 = w4[4 * jn + 3];
        { f32x2 W = { p0.x, p0.y }; BMC_STEP(W) }
        { f32x2 W = { p0.z, p0.w }; BMC_STEP(W) }
        { f32x2 W = { p1.x, p1.y }; BMC_STEP(W) }
        { f32x2 W = { p1.z, p1.w }; BMC_STEP(W) }
        { f32x2 W = { p2.x, p2.y }; BMC_STEP(W) }
        { f32x2 W = { p2.z, p2.w }; BMC_STEP(W) }
        { f32x2 W = { p3.x, p3.y }; BMC_STEP(W) }
        { f32x2 W = { p3.z, p3.w }; BMC_STEP(W) }
        p0 = n0; p1 = n1; p2 = n2; p3 = n3;
    }
#undef BMC_STEP
#undef TERMX_TREE
#undef TERMX_TREE_B

    // wave-64 max reduce, then one atomic per wave (sim uniform per wave)
    for (int d = 32; d >= 1; d >>= 1)
        lmax = fmaxf(lmax, __shfl_xor(lmax, d, 64));
    if ((threadIdx.x & 63) == 0)
        atomicMax(gmax + sim, __float_as_uint(lmax));   // all values >= 0

    (void)NSAMP;
}

__global__ void finalize_kernel(const unsigned int* __restrict__ gmax,
                                float* __restrict__ out) {
    int i = threadIdx.x;
    if (i < 2) out[i] = sqrtf(__uint_as_float(gmax[i]));   // float32 output
}

extern "C" void kernel_launch(void* const* d_in, const int* in_sizes, int n_in,
                              void* d_out, int out_size, void* d_ws, size_t ws_size,
                              hipStream_t stream) {
    const float* amps    = (const float*)d_in[0];   // (4,128)
    const float* phases  = (const float*)d_in[1];   // (4,128)
    const float* offsets = (const float*)d_in[2];   // (32768,)
    const float* m_init  = (const float*)d_in[3];   // (6,)
    float* out           = (float*)d_out;           // (2,) float32

    unsigned int* gmax = (unsigned int*)d_ws;                 // 2 slots
    float2* wsc = (float2*)((char*)d_ws + 256);               // 2*512 float2

    // Python-semantics accumulated phase per (sim, rf block), computed in f64
    AccPh acc;
    for (int s = 0; s < 2; ++s) {
        double rfo  = s ? -200.0 : 200.0;
        double accp = 0.0;
        for (int r = 0; r < NRF; ++r) {
            acc.a[s * 4 + r] = (float)accp;
            double pd = fmod(3.9e-05 * 128.0 * 360.0 * rfo, 360.0);
            if (pd < 0.0) pd += 360.0;      // Python % semantics
            accp += pd / 180.0 * M_PI;
        }
    }

    init_kernel<<<1, 64, 0, stream>>>(gmax);
    precomp_kernel<<<4, 256, 0, stream>>>(amps, phases, acc, wsc);
    bmc_kernel<<<(2 * NOFF) / 256, 256, 0, stream>>>(offsets, m_init, wsc, gmax);
    finalize_kernel<<<1, 64, 0, stream>>>(gmax, out);
}

// Round 8
// 67.165 us; speedup vs baseline: 1.6511x; 1.6511x over previous
//
#include <hip/hip_runtime.h>
#include <hip/hip_bf16.h>
#include <math.h>

// ---- constants mirroring the reference ----
#define TWO_PI_D 6.283185307179586
constexpr int   NOFF  = 32768;
constexpr int   NSAMP = 128;
constexpr int   NRF   = 4;
constexpr int   NSTEP = NRF * NSAMP;   // 512
constexpr float DT    = 3.9e-05f;
constexpr double DTD  = 3.9e-05;
constexpr float R1A   = 1.0f / 1.3f;
constexpr float R2A   = 1.0f / 0.075f;
constexpr float R1B   = 1.0f;
constexpr float R2B   = 30.0f;
constexpr float KBv   = 200.0f;
constexpr float FBv   = 0.01f;
constexpr float KAv   = FBv * KBv;     // 2.0
constexpr float DWB   = 447.0f;

typedef float f32x2 __attribute__((ext_vector_type(2)));
typedef float f32x4 __attribute__((ext_vector_type(4)));

// ---- VOP3P packed-f32 helpers (validated on HW in rounds 6/7) ----
#define PK_ADD(d, a, b) \
    asm("v_pk_add_f32 %0, %1, %2" : "=v"(d) : "v"(a), "v"(b))
#define PK_FMA(d, a, b, c) \
    asm("v_pk_fma_f32 %0, %1, %2, %3" : "=v"(d) : "v"(a), "v"(b), "v"(c))
#define PK_FMA_ACC(acc, a, b) \
    asm("v_pk_fma_f32 %0, %1, %2, %0" : "+v"(acc) : "v"(a), "v"(b))
// dup LOW / HIGH half of src0 pair into both mul lanes (coeff broadcast)
#define PK_MUL_S0LO(d, p, s) \
    asm("v_pk_mul_f32 %0, %1, %2 op_sel:[0,0] op_sel_hi:[0,1]" : "=v"(d) : "v"(p), "v"(s))
#define PK_MUL_S0HI(d, p, s) \
    asm("v_pk_mul_f32 %0, %1, %2 op_sel:[1,0] op_sel_hi:[1,1]" : "=v"(d) : "v"(p), "v"(s))
#define PK_MUL_S0LO_NEG(d, p, s) \
    asm("v_pk_mul_f32 %0, %1, %2 op_sel:[0,0] op_sel_hi:[0,1] neg_lo:[1,0] neg_hi:[1,0]" : "=v"(d) : "v"(p), "v"(s))
#define PK_FMA_ACC_S0LO(acc, p, s) \
    asm("v_pk_fma_f32 %0, %1, %2, %0 op_sel:[0,0,0] op_sel_hi:[0,1,1]" : "+v"(acc) : "v"(p), "v"(s))
#define PK_FMA_ACC_S0HI(acc, p, s) \
    asm("v_pk_fma_f32 %0, %1, %2, %0 op_sel:[1,0,0] op_sel_hi:[1,1,1]" : "+v"(acc) : "v"(p), "v"(s))
#define PK_FMA_ACC_S0HI_NEG(acc, p, s) \
    asm("v_pk_fma_f32 %0, %1, %2, %0 op_sel:[1,0,0] op_sel_hi:[1,1,1] neg_lo:[1,0,0] neg_hi:[1,0,0]" : "+v"(acc) : "v"(p), "v"(s))
// cross-pool terms: d.lo (+)= a.lo*s.hi ; d.hi (+)= a.hi*s.lo
#define PK_MUL_SWAP1(d, a, s) \
    asm("v_pk_mul_f32 %0, %1, %2 op_sel:[0,1] op_sel_hi:[1,0]" : "=v"(d) : "v"(a), "v"(s))
#define PK_FMA_ACC_SWAP1(acc, a, s) \
    asm("v_pk_fma_f32 %0, %1, %2, %0 op_sel:[0,1,0] op_sel_hi:[1,0,1]" : "+v"(acc) : "v"(a), "v"(s))

struct AccPhD { double a[8]; };        // [sim][rf_block] accumulated phase (f64)

// Per-(sim,step) EXACT RF rotation R = exp(W*DT): Rodrigues about in-plane
// axis n = (-cos ph, -sin ph, 0), angle th = w1*DT. 6 distinct coeffs
// (r20=-r02, r21=-r12, r10=r01). Stored as 8 floats: [r00,r01,r02,r12][r11,r22,0,0].
__global__ void rot_table_kernel(const float* __restrict__ amps,
                                 const float* __restrict__ phases,
                                 AccPhD acc, float4* __restrict__ rt4) {
    int tid = blockIdx.x * blockDim.x + threadIdx.x;   // 0..1023
    if (tid >= 2 * NSTEP) return;
    int sim = tid >> 9;
    int idx = tid & (NSTEP - 1);
    int r   = idx >> 7;
    double ph = -(double)phases[idx] - acc.a[sim * 4 + r];
    double w1 = TWO_PI_D * 42.577 * (double)amps[idx];
    double th = w1 * DTD;
    double sn = sin(th), cs = cos(th), Cc = 1.0 - cs;
    double nx = -cos(ph), ny = -sin(ph);
    float r00 = (float)(cs + nx * nx * Cc);
    float r01 = (float)(nx * ny * Cc);
    float r02 = (float)(ny * sn);
    float r12 = (float)(-nx * sn);
    float r11 = (float)(cs + ny * ny * Cc);
    float r22 = (float)cs;
    rt4[2 * tid]     = make_float4(r00, r01, r02, r12);
    rt4[2 * tid + 1] = make_float4(r11, r22, 0.0f, 0.0f);
}

__global__ void init_kernel(unsigned int* g) {
    if (threadIdx.x < 2) g[threadIdx.x] = 0u;
}

__global__ __launch_bounds__(256, 1) void bmc_kernel(
        const float* __restrict__ offsets,
        const float* __restrict__ m_init,
        const float* __restrict__ rt,
        unsigned int* __restrict__ gmax) {
    int tid = blockIdx.x * blockDim.x + threadIdx.x;   // 0..65535
    int sim = tid >> 15;
    int o   = tid & (NOFF - 1);

    const float TP  = (float)TWO_PI_D;
    float rf  = sim ? -200.0f : 200.0f;
    float off = offsets[o];
    float dwa = TP * (off - rf);
    float dwb = TP * ((off + DWB) - rf);

    // ---- one-time: Eh = exp(D~ * DT/2) (augmented 6x7, order-9 Taylor),
    //      then Ef = Eh*Eh (full step). D~ = [[D, b],[0,0]], D = drift. ----
    const float h     = 0.5f * DT;
    const float ca_h  = -(R2A + KAv) * h;
    const float cb_h  = -(R1A + KAv) * h;
    const float cc_h  = -(R2B + KBv) * h;
    const float cd_h  = -(R1B + KBv) * h;
    const float ka_h  = KAv * h, kb_h = KBv * h;
    const float dwa_h = dwa * h, dwb_h = dwb * h;
    const float b2_h  = R1A * h, b5_h = R1B * FBv * h;

    float Eh[6][7], U[6][7];
#pragma unroll
    for (int i = 0; i < 6; ++i)
#pragma unroll
        for (int j = 0; j < 7; ++j) {
            float v = (i == j) ? 1.0f : 0.0f;
            Eh[i][j] = v; U[i][j] = v;
        }
#pragma unroll
    for (int k = 1; k <= 9; ++k) {
        const float rk = 1.0f / (float)k;
        float N[6][7];
#pragma unroll
        for (int i = 0; i < 6; ++i) {
            N[i][0] = U[i][0] * ca_h  - U[i][1] * dwa_h + U[i][3] * ka_h;
            N[i][1] = U[i][0] * dwa_h + U[i][1] * ca_h  + U[i][4] * ka_h;
            N[i][2] = U[i][2] * cb_h  + U[i][5] * ka_h;
            N[i][3] = U[i][0] * kb_h  + U[i][3] * cc_h  - U[i][4] * dwb_h;
            N[i][4] = U[i][1] * kb_h  + U[i][3] * dwb_h + U[i][4] * cc_h;
            N[i][5] = U[i][2] * kb_h  + U[i][5] * cd_h;
            N[i][6] = U[i][2] * b2_h  + U[i][5] * b5_h;
        }
#pragma unroll
        for (int i = 0; i < 6; ++i)
#pragma unroll
            for (int j = 0; j < 7; ++j) {
                U[i][j] = N[i][j] * rk;
                Eh[i][j] += U[i][j];
            }
    }
    float Ef[6][7];
#pragma unroll
    for (int i = 0; i < 6; ++i)
#pragma unroll
        for (int j = 0; j < 7; ++j) {
            float s = (j == 6) ? Eh[i][6] : 0.0f;
#pragma unroll
            for (int k2 = 0; k2 < 6; ++k2) s += Eh[i][k2] * Eh[k2][j];
            Ef[i][j] = s;
        }

    // pair constants: pair X = (pool-a comp, pool-b comp); rows (0,3),(1,4),(2,5)
    const f32x2 DD_AA = { Ef[0][0], Ef[3][3] }, DD_AB = { Ef[0][1], Ef[3][4] }, DD_AC = { Ef[0][2], Ef[3][5] };
    const f32x2 CC_AA = { Ef[0][3], Ef[3][0] }, CC_AB = { Ef[0][4], Ef[3][1] }, CC_AC = { Ef[0][5], Ef[3][2] };
    const f32x2 DD_BA = { Ef[1][0], Ef[4][3] }, DD_BB = { Ef[1][1], Ef[4][4] }, DD_BC = { Ef[1][2], Ef[4][5] };
    const f32x2 CC_BA = { Ef[1][3], Ef[4][0] }, CC_BB = { Ef[1][4], Ef[4][1] }, CC_BC = { Ef[1][5], Ef[4][2] };
    const f32x2 DD_CA = { Ef[2][0], Ef[5][3] }, DD_CB = { Ef[2][1], Ef[5][4] }, DD_CC = { Ef[2][2], Ef[5][5] };
    const f32x2 CC_CA = { Ef[2][3], Ef[5][0] }, CC_CB = { Ef[2][4], Ef[5][1] }, CC_CC = { Ef[2][5], Ef[5][2] };
    const f32x2 qA = { Ef[0][6], Ef[3][6] }, qB = { Ef[1][6], Ef[4][6] }, qC = { Ef[2][6], Ef[5][6] };

    // ---- pre: m = Eh * [m_init; 1]  (enter the half-shifted Strang frame) ----
    float x0 = m_init[0], x1 = m_init[1], x2 = m_init[2];
    float x3 = m_init[3], x4 = m_init[4], x5 = m_init[5];
    float mi[6];
#pragma unroll
    for (int i = 0; i < 6; ++i)
        mi[i] = Eh[i][6] + Eh[i][0]*x0 + Eh[i][1]*x1 + Eh[i][2]*x2
                         + Eh[i][3]*x3 + Eh[i][4]*x4 + Eh[i][5]*x5;
    f32x2 mA = { mi[0], mi[3] }, mB = { mi[1], mi[4] }, mC = { mi[2], mi[5] };
    float lmax = 0.0f;

    // ---- per step: m <- Ef * (R(s) * m) + q.  38 VALU, critical path 7. ----
#define FULL_STEP(t4a, t4b)                                                    \
    {                                                                          \
        f32x2 P1 = __builtin_shufflevector(t4a, t4a, 0, 1);                    \
        f32x2 P2 = __builtin_shufflevector(t4a, t4a, 2, 3);                    \
        f32x2 P3 = __builtin_shufflevector(t4b, t4b, 0, 1);                    \
        f32x2 xA, xB, xC, d1, d2, e1, e2, f1, f2;                              \
        PK_MUL_S0LO(xA, P1, mA);                                               \
        PK_MUL_S0HI(xB, P1, mA);                                               \
        PK_MUL_S0LO_NEG(xC, P2, mA);                                           \
        PK_FMA_ACC_S0HI(xA, P1, mB);                                           \
        PK_FMA_ACC_S0LO(xB, P3, mB);                                           \
        PK_FMA_ACC_S0HI_NEG(xC, P2, mB);                                       \
        PK_FMA_ACC_S0LO(xA, P2, mC);                                           \
        PK_FMA_ACC_S0HI(xB, P2, mC);                                           \
        PK_FMA_ACC_S0HI(xC, P3, mC);                                           \
        PK_FMA(d1, DD_AA, xA, qA);                                             \
        PK_FMA(e1, DD_BA, xA, qB);                                             \
        PK_FMA(f1, DD_CA, xA, qC);                                             \
        PK_MUL_SWAP1(d2, CC_AA, xA);                                           \
        PK_MUL_SWAP1(e2, CC_BA, xA);                                           \
        PK_MUL_SWAP1(f2, CC_CA, xA);                                           \
        PK_FMA_ACC(d1, DD_AB, xB);                                             \
        PK_FMA_ACC(e1, DD_BB, xB);                                             \
        PK_FMA_ACC(f1, DD_CB, xB);                                             \
        PK_FMA_ACC_SWAP1(d2, CC_AB, xB);                                       \
        PK_FMA_ACC_SWAP1(e2, CC_BB, xB);                                       \
        PK_FMA_ACC_SWAP1(f2, CC_CB, xB);                                       \
        PK_FMA_ACC(d1, DD_AC, xC);                                             \
        PK_FMA_ACC(e1, DD_BC, xC);                                             \
        PK_FMA_ACC(f1, DD_CC, xC);                                             \
        PK_FMA_ACC_SWAP1(d2, CC_AC, xC);                                       \
        PK_FMA_ACC_SWAP1(e2, CC_BC, xC);                                       \
        PK_FMA_ACC_SWAP1(f2, CC_CC, xC);                                       \
        PK_ADD(mA, d1, d2);                                                    \
        PK_ADD(mB, e1, e2);                                                    \
        PK_ADD(mC, f1, f2);                                                    \
        lmax = fmaxf(lmax, fmaf(mA.x, mA.x, mB.x * mB.x));                     \
    }

    const f32x4* __restrict__ rt4 = (const f32x4*)rt + (size_t)sim * NSTEP * 2;
    f32x4 c0 = rt4[0], c1 = rt4[1], c2 = rt4[2], c3 = rt4[3];
    f32x4 c4 = rt4[4], c5 = rt4[5], c6 = rt4[6], c7 = rt4[7];
#pragma unroll 1
    for (int j = 0; j < 127; ++j) {              // steps 0..507
        int nb = (j + 1) * 8;
        f32x4 n0 = rt4[nb+0], n1 = rt4[nb+1], n2 = rt4[nb+2], n3 = rt4[nb+3];
        f32x4 n4 = rt4[nb+4], n5 = rt4[nb+5], n6 = rt4[nb+6], n7 = rt4[nb+7];
        FULL_STEP(c0, c1)
        FULL_STEP(c2, c3)
        FULL_STEP(c4, c5)
        FULL_STEP(c6, c7)
        c0 = n0; c1 = n1; c2 = n2; c3 = n3;
        c4 = n4; c5 = n5; c6 = n6; c7 = n7;
    }
    // tail: steps 508..510 full
    FULL_STEP(c0, c1)
    FULL_STEP(c2, c3)
    FULL_STEP(c4, c5)
    // step 511: rotation, then HALF drift (exit the Strang frame exactly)
    {
        f32x2 P1 = __builtin_shufflevector(c6, c6, 0, 1);
        f32x2 P2 = __builtin_shufflevector(c6, c6, 2, 3);
        f32x2 P3 = __builtin_shufflevector(c7, c7, 0, 1);
        f32x2 xA, xB, xC;
        PK_MUL_S0LO(xA, P1, mA);
        PK_MUL_S0HI(xB, P1, mA);
        PK_MUL_S0LO_NEG(xC, P2, mA);
        PK_FMA_ACC_S0HI(xA, P1, mB);
        PK_FMA_ACC_S0LO(xB, P3, mB);
        PK_FMA_ACC_S0HI_NEG(xC, P2, mB);
        PK_FMA_ACC_S0LO(xA, P2, mC);
        PK_FMA_ACC_S0HI(xB, P2, mC);
        PK_FMA_ACC_S0HI(xC, P3, mC);
        float y0 = xA.x, y3 = xA.y, y1 = xB.x, y4 = xB.y, y2 = xC.x, y5 = xC.y;
        float f0 = Eh[0][6] + Eh[0][0]*y0 + Eh[0][1]*y1 + Eh[0][2]*y2
                            + Eh[0][3]*y3 + Eh[0][4]*y4 + Eh[0][5]*y5;
        float f1s = Eh[1][6] + Eh[1][0]*y0 + Eh[1][1]*y1 + Eh[1][2]*y2
                             + Eh[1][3]*y3 + Eh[1][4]*y4 + Eh[1][5]*y5;
        lmax = fmaxf(lmax, fmaf(f0, f0, f1s * f1s));
    }
#undef FULL_STEP

    // wave-64 max reduce, then one atomic per wave (sim uniform per wave)
    for (int d = 32; d >= 1; d >>= 1)
        lmax = fmaxf(lmax, __shfl_xor(lmax, d, 64));
    if ((threadIdx.x & 63) == 0)
        atomicMax(gmax + sim, __float_as_uint(lmax));   // all values >= 0

    (void)NSAMP;
}

__global__ void finalize_kernel(const unsigned int* __restrict__ gmax,
                                float* __restrict__ out) {
    int i = threadIdx.x;
    if (i < 2) out[i] = sqrtf(__uint_as_float(gmax[i]));   // float32 output
}

extern "C" void kernel_launch(void* const* d_in, const int* in_sizes, int n_in,
                              void* d_out, int out_size, void* d_ws, size_t ws_size,
                              hipStream_t stream) {
    const float* amps    = (const float*)d_in[0];   // (4,128)
    const float* phases  = (const float*)d_in[1];   // (4,128)
    const float* offsets = (const float*)d_in[2];   // (32768,)
    const float* m_init  = (const float*)d_in[3];   // (6,)
    float* out           = (float*)d_out;           // (2,) float32

    unsigned int* gmax = (unsigned int*)d_ws;                 // 2 slots
    float* rt = (float*)((char*)d_ws + 256);                  // 2*512*8 floats = 32 KB

    // Python-semantics accumulated phase per (sim, rf block), in f64
    AccPhD acc;
    for (int s = 0; s < 2; ++s) {
        double rfo  = s ? -200.0 : 200.0;
        double accp = 0.0;
        for (int r = 0; r < NRF; ++r) {
            acc.a[s * 4 + r] = accp;
            double pd = fmod(3.9e-05 * 128.0 * 360.0 * rfo, 360.0);
            if (pd < 0.0) pd += 360.0;      // Python % semantics
            accp += pd / 180.0 * M_PI;
        }
    }

    init_kernel<<<1, 64, 0, stream>>>(gmax);
    rot_table_kernel<<<4, 256, 0, stream>>>(amps, phases, acc, (float4*)rt);
    bmc_kernel<<<(2 * NOFF) / 256, 256, 0, stream>>>(offsets, m_init, rt, gmax);
    finalize_kernel<<<1, 64, 0, stream>>>(gmax, out);
}